// Round 8
// baseline (171.713 us; speedup 1.0000x reference)
//
#include <hip/hip_runtime.h>

// Sparse residual block via bf16 MFMA, output-centric.
// Round 8: "free-wave" — one independent wave per 32-row x 96-cout tile.
// No LDS, no barriers, no inline asm. B frags read from global in read-order
// layout (1KB coalesced dwordx4 each, L1/L2-hot); compiler free-pipelines.

typedef __attribute__((ext_vector_type(8))) short bf16x8;
typedef __attribute__((ext_vector_type(4))) float f32x4;
typedef unsigned short u16;

constexpr int K27  = 27;
constexpr int KPAD = 32;     // nbT k-slots (27..31 always invalid = -1)
constexpr int CIN  = 64;
constexpr int COUT = 96;
constexpr int W1SZ = 6144;   // u16 per k-tile: 12 frags * 512
constexpr int W2SZ = 9216;   // u16 per k-tile: 18 frags * 512

#define MFMA __builtin_amdgcn_mfma_f32_16x16x32_bf16

__device__ __forceinline__ u16 f2bf(float f) {
  unsigned u = __float_as_uint(f);
  return (u16)((u + 0x7FFFu + ((u >> 16) & 1u)) >> 16);
}

__device__ __forceinline__ int posf(int c) {  // c in 0..31, k_local-ordered perm
  return ((c >> 2) & 3) * 8 + (c & 3) + ((c >> 4) & 1) * 4;
}

__device__ __forceinline__ bf16x8 ld16(const u16* p) {
  union { bf16x8 f; uint4 u; } r;
  r.u = *reinterpret_cast<const uint4*>(p);
  return r.f;
}

// bijective XCD-aware swizzle (m204 form)
__device__ __forceinline__ int xcd_swz(int bid, int nblk) {
  int q = nblk >> 3, r = nblk & 7;
  int x = bid & 7, i = bid >> 3;
  return (x < r ? x * (q + 1) : r * (q + 1) + (x - r) * q) + i;
}

// ---------------- prep ----------------
__global__ void build_nbT(const int* __restrict__ in_idx, const int* __restrict__ out_idx,
                          int* __restrict__ nbT, int N, int N_pad) {
  int t = blockIdx.x * blockDim.x + threadIdx.x;
  if (t >= K27 * N) return;
  int k = t / N;
  int o = out_idx[t];
  if (o < N) nbT[(size_t)k * N_pad + o] = in_idx[t];
}

__global__ void prep_all(
    const float* __restrict__ x, const float* __restrict__ W1,
    const float* __restrict__ W2, const float* __restrict__ Wd,
    const float* g1, const float* b1, const float* m1, const float* v1,
    const float* g2, const float* b2, const float* m2, const float* v2,
    const float* gd, const float* bd, const float* md, const float* vd,
    u16* __restrict__ xbf, u16* __restrict__ W1t, u16* __restrict__ W2t,
    u16* __restrict__ Wdt, float* __restrict__ bnc, u16* __restrict__ hbf, int N) {
  long i = (long)blockIdx.x * blockDim.x + threadIdx.x;
  const long R0 = (long)(N + 1) * CIN;
  const long R1 = (long)K27 * W1SZ;
  const long R2 = (long)K27 * W2SZ;
  const long R3 = (long)CIN * COUT;
  if (i < R0) {  // x -> bf16, permuted channels; row N zeroed
    int c = (int)(i & 63);
    float v = (i < (long)N * CIN) ? x[i] : 0.f;
    xbf[(i & ~63L) + (c & 32) + posf(c & 31)] = f2bf(v);
    return;
  }
  i -= R0;
  if (i < R1) {  // W1 -> read-order frags: [k][f=c*6+n][lane][j]
    int k = (int)(i / W1SZ), r = (int)(i % W1SZ);
    int f = r >> 9, lane = (r >> 3) & 63, j = r & 7;
    int c = f / 6, n = f % 6, m = lane & 15, g = lane >> 4;
    int co = n * 16 + m;
    int ci = c * 32 + 4 * g + (j & 3) + 16 * (j >> 2);
    W1t[i] = f2bf(W1[((size_t)k * CIN + ci) * COUT + co]);
    return;
  }
  i -= R1;
  if (i < R2) {  // W2 -> read-order frags
    int k = (int)(i / W2SZ), r = (int)(i % W2SZ);
    int f = r >> 9, lane = (r >> 3) & 63, j = r & 7;
    int c = f / 6, n = f % 6, m = lane & 15, g = lane >> 4;
    int co = n * 16 + m;
    int ci = c * 32 + 4 * g + (j & 3) + 16 * (j >> 2);
    W2t[i] = f2bf(W2[((size_t)k * COUT + ci) * COUT + co]);
    return;
  }
  i -= R2;
  if (i < R3) {  // Wd[ci][co] -> Wdt[co][perm(ci)] (register path)
    int ci = (int)(i / COUT), co = (int)(i % COUT);
    Wdt[co * CIN + (ci & 32) + posf(ci & 31)] = f2bf(Wd[i]);
    return;
  }
  i -= R3;
  if (i < COUT) {
    int c = (int)i;
    float A1 = g1[c] * rsqrtf(v1[c] + 1e-5f);
    float A2 = g2[c] * rsqrtf(v2[c] + 1e-5f);
    float Ad = gd[c] * rsqrtf(vd[c] + 1e-5f);
    bnc[c]       = A1;
    bnc[96 + c]  = b1[c] - m1[c] * A1;
    bnc[192 + c] = A2;
    bnc[288 + c] = b2[c] - m2[c] * A2 + bd[c] - md[c] * Ad;
    bnc[384 + c] = Ad / A2;
    hbf[(size_t)N * COUT + c] = 0;
  }
}

// ---------------- conv1: x(64) -> h(96) bf16, BN+ReLU, permuted store --------
__global__ __launch_bounds__(64, 4) void conv1_mfma(
    const u16* __restrict__ xbf, const u16* __restrict__ W1t,
    const int* __restrict__ nbT, const float* __restrict__ bnc,
    u16* __restrict__ hbf, int N, int N_pad) {
  const int lane = threadIdx.x & 63;
  const int m    = lane & 15;
  const int slot = lane >> 4;
  const int so   = slot * 8;
  const int roww = xcd_swz(blockIdx.x, gridDim.x) * 32;

  f32x4 acc[2][6];
#pragma unroll
  for (int s = 0; s < 2; ++s)
#pragma unroll
    for (int n = 0; n < 6; ++n) acc[s][n] = (f32x4){0.f, 0.f, 0.f, 0.f};

  const int* nbp = nbT + roww + m;

  int j1a, j1b, j2a, j2b;
  bf16x8 Aa[2][2], Ab[2][2];
  {
    int j0a = nbp[0], j0b = nbp[16];
    j1a = nbp[N_pad];             j1b = nbp[N_pad + 16];
    j2a = nbp[2 * (size_t)N_pad]; j2b = nbp[2 * (size_t)N_pad + 16];
    const u16* pa = xbf + (size_t)(j0a < 0 ? N : j0a) * CIN + so;
    const u16* pb = xbf + (size_t)(j0b < 0 ? N : j0b) * CIN + so;
    Aa[0][0] = ld16(pa); Aa[0][1] = ld16(pa + 32);
    Aa[1][0] = ld16(pb); Aa[1][1] = ld16(pb + 32);
  }

  auto step = [&](int k, bf16x8 (&Ac)[2][2], bf16x8 (&An)[2][2]) {
    {  // A(k+1) prefetch (distance 1), j ring at distance 3
      const u16* pa = xbf + (size_t)(j1a < 0 ? N : j1a) * CIN + so;
      const u16* pb = xbf + (size_t)(j1b < 0 ? N : j1b) * CIN + so;
      An[0][0] = ld16(pa); An[0][1] = ld16(pa + 32);
      An[1][0] = ld16(pb); An[1][1] = ld16(pb + 32);
    }
    int j3a = nbp[(size_t)(k + 3) * N_pad];
    int j3b = nbp[(size_t)(k + 3) * N_pad + 16];
    j1a = j2a; j1b = j2b; j2a = j3a; j2b = j3b;
    const u16* wk = W1t + (size_t)k * W1SZ + lane * 8;
#pragma unroll
    for (int c = 0; c < 2; ++c)
#pragma unroll
      for (int n = 0; n < 6; ++n) {
        bf16x8 B = ld16(wk + (c * 6 + n) * 512);
        acc[0][n] = MFMA(Ac[0][c], B, acc[0][n], 0, 0, 0);
        acc[1][n] = MFMA(Ac[1][c], B, acc[1][n], 0, 0, 0);
      }
  };

  for (int kk = 0; kk < K27 - 1; kk += 2) {
    step(kk, Aa, Ab);
    step(kk + 1, Ab, Aa);
  }
  step(K27 - 1, Aa, Ab);

  const int pbase = ((m >> 2) << 3) + (m & 3);
#pragma unroll
  for (int n = 0; n < 6; ++n) {
    const int col  = n * 16 + m;
    const int dcol = (n >> 1) * 32 + pbase + ((n & 1) << 2);  // perm pos for conv2 A
    const float sc = bnc[col], bi = bnc[COUT + col];
#pragma unroll
    for (int s = 0; s < 2; ++s)
#pragma unroll
      for (int r = 0; r < 4; ++r) {
        const int row = roww + s * 16 + slot * 4 + r;
        if (row < N)
          hbf[(size_t)row * COUT + dcol] = f2bf(fmaxf(fmaf(acc[s][n][r], sc, bi), 0.f));
      }
  }
}

// ------- conv2: h(96) -> out(96) f32, + folded skip BN(x@Wd), BN+ReLU --------
__global__ __launch_bounds__(64, 3) void conv2_mfma(
    const u16* __restrict__ hbf, const u16* __restrict__ W2t,
    const u16* __restrict__ xbf, const u16* __restrict__ Wdt,
    const int* __restrict__ nbT, const float* __restrict__ bnc,
    float* __restrict__ out, int N, int N_pad) {
  const int lane = threadIdx.x & 63;
  const int m    = lane & 15;
  const int slot = lane >> 4;
  const int so   = slot * 8;
  const int roww = xcd_swz(blockIdx.x, gridDim.x) * 32;

  f32x4 acc[2][6];
#pragma unroll
  for (int s = 0; s < 2; ++s)
#pragma unroll
    for (int n = 0; n < 6; ++n) acc[s][n] = (f32x4){0.f, 0.f, 0.f, 0.f};

  // skip path: x @ Wd on own rows, pre-scaled by Ad/A2
  {
    int r0 = roww + m, r1 = roww + 16 + m;
    const u16* pa = xbf + (size_t)(r0 < N ? r0 : N) * CIN + so;
    const u16* pb = xbf + (size_t)(r1 < N ? r1 : N) * CIN + so;
    bf16x8 S0a = ld16(pa), S1a = ld16(pa + 32);
    bf16x8 S0b = ld16(pb), S1b = ld16(pb + 32);
#pragma unroll
    for (int n = 0; n < 6; ++n) {
      const int col = n * 16 + m;
      const u16* wd = Wdt + col * CIN + so;
      bf16x8 B0 = ld16(wd), B1 = ld16(wd + 32);
      acc[0][n] = MFMA(S0a, B0, acc[0][n], 0, 0, 0);
      acc[0][n] = MFMA(S1a, B1, acc[0][n], 0, 0, 0);
      acc[1][n] = MFMA(S0b, B0, acc[1][n], 0, 0, 0);
      acc[1][n] = MFMA(S1b, B1, acc[1][n], 0, 0, 0);
    }
#pragma unroll
    for (int n = 0; n < 6; ++n) {
      float rr = bnc[384 + n * 16 + m];
      acc[0][n] *= rr;
      acc[1][n] *= rr;
    }
  }

  const int* nbp = nbT + roww + m;
  int j1a, j1b, j2a, j2b;
  bf16x8 Aa[2][3], Ab[2][3];
  {
    int j0a = nbp[0], j0b = nbp[16];
    j1a = nbp[N_pad];             j1b = nbp[N_pad + 16];
    j2a = nbp[2 * (size_t)N_pad]; j2b = nbp[2 * (size_t)N_pad + 16];
    const u16* pa = hbf + (size_t)(j0a < 0 ? N : j0a) * COUT + so;
    const u16* pb = hbf + (size_t)(j0b < 0 ? N : j0b) * COUT + so;
    Aa[0][0] = ld16(pa); Aa[0][1] = ld16(pa + 32); Aa[0][2] = ld16(pa + 64);
    Aa[1][0] = ld16(pb); Aa[1][1] = ld16(pb + 32); Aa[1][2] = ld16(pb + 64);
  }

  auto step = [&](int k, bf16x8 (&Ac)[2][3], bf16x8 (&An)[2][3]) {
    {  // A(k+1) prefetch (distance 1), j ring at distance 3
      const u16* pa = hbf + (size_t)(j1a < 0 ? N : j1a) * COUT + so;
      const u16* pb = hbf + (size_t)(j1b < 0 ? N : j1b) * COUT + so;
      An[0][0] = ld16(pa); An[0][1] = ld16(pa + 32); An[0][2] = ld16(pa + 64);
      An[1][0] = ld16(pb); An[1][1] = ld16(pb + 32); An[1][2] = ld16(pb + 64);
    }
    int j3a = nbp[(size_t)(k + 3) * N_pad];
    int j3b = nbp[(size_t)(k + 3) * N_pad + 16];
    j1a = j2a; j1b = j2b; j2a = j3a; j2b = j3b;
    const u16* wk = W2t + (size_t)k * W2SZ + lane * 8;
#pragma unroll
    for (int c = 0; c < 3; ++c)
#pragma unroll
      for (int n = 0; n < 6; ++n) {
        bf16x8 B = ld16(wk + (c * 6 + n) * 512);
        acc[0][n] = MFMA(Ac[0][c], B, acc[0][n], 0, 0, 0);
        acc[1][n] = MFMA(Ac[1][c], B, acc[1][n], 0, 0, 0);
      }
  };

  for (int kk = 0; kk < K27 - 1; kk += 2) {
    step(kk, Aa, Ab);
    step(kk + 1, Ab, Aa);
  }
  step(K27 - 1, Aa, Ab);

#pragma unroll
  for (int n = 0; n < 6; ++n) {
    const int col = n * 16 + m;
    const float sc = bnc[192 + col], bi = bnc[288 + col];
#pragma unroll
    for (int s = 0; s < 2; ++s)
#pragma unroll
      for (int r = 0; r < 4; ++r) {
        const int row = roww + s * 16 + slot * 4 + r;
        if (row < N)
          out[(size_t)row * COUT + col] = fmaxf(fmaf(acc[s][n][r], sc, bi), 0.f);
      }
  }
}

// ---------------- launch ----------------
extern "C" void kernel_launch(void* const* d_in, const int* in_sizes, int n_in,
                              void* d_out, int out_size, void* d_ws, size_t ws_size,
                              hipStream_t stream) {
  const float* x  = (const float*)d_in[0];
  const float* W1 = (const float*)d_in[1];
  const float* g1 = (const float*)d_in[2];
  const float* b1 = (const float*)d_in[3];
  const float* m1 = (const float*)d_in[4];
  const float* v1 = (const float*)d_in[5];
  const float* W2 = (const float*)d_in[6];
  const float* g2 = (const float*)d_in[7];
  const float* b2 = (const float*)d_in[8];
  const float* m2 = (const float*)d_in[9];
  const float* v2 = (const float*)d_in[10];
  const float* Wd = (const float*)d_in[11];
  const float* gd = (const float*)d_in[12];
  const float* bd = (const float*)d_in[13];
  const float* md = (const float*)d_in[14];
  const float* vd = (const float*)d_in[15];
  const int* in_idx  = (const int*)d_in[16];
  const int* out_idx = (const int*)d_in[17];

  const int N    = in_sizes[0] / CIN;
  const int GB32 = (N + 31) / 32;            // 1 wave (32 rows) per block
  const int N_pad = ((N + 63) / 64) * 64;

  char* ws = (char*)d_ws;
  size_t off = 0;
  auto alloc = [&](size_t bytes) { size_t o = off; off = (off + bytes + 255) & ~(size_t)255; return o; };
  int*   nbT = (int*)(ws + alloc((size_t)KPAD * N_pad * sizeof(int)));
  u16*   xbf = (u16*)(ws + alloc((size_t)(N + 1) * CIN * sizeof(u16)));
  u16*   hbf = (u16*)(ws + alloc((size_t)(N + 1) * COUT * sizeof(u16)));
  u16*   W1t = (u16*)(ws + alloc((size_t)K27 * W1SZ * sizeof(u16)));
  u16*   W2t = (u16*)(ws + alloc((size_t)K27 * W2SZ * sizeof(u16)));
  u16*   Wdt = (u16*)(ws + alloc((size_t)COUT * CIN * sizeof(u16)));
  float* bnc = (float*)(ws + alloc(5 * 96 * sizeof(float)));

  hipMemsetAsync(nbT, 0xFF, (size_t)KPAD * N_pad * sizeof(int), stream);
  build_nbT<<<(K27 * N + 255) / 256, 256, 0, stream>>>(in_idx, out_idx, nbT, N, N_pad);

  long ptotal = (long)(N + 1) * CIN + (long)K27 * W1SZ + (long)K27 * W2SZ +
                (long)CIN * COUT + COUT;
  prep_all<<<(int)((ptotal + 255) / 256), 256, 0, stream>>>(
      x, W1, W2, Wd, g1, b1, m1, v1, g2, b2, m2, v2, gd, bd, md, vd,
      xbf, W1t, W2t, Wdt, bnc, hbf, N);

  conv1_mfma<<<GB32, 64, 0, stream>>>(xbf, W1t, nbT, bnc, hbf, N, N_pad);
  conv2_mfma<<<GB32, 64, 0, stream>>>(hbf, W2t, xbf, Wdt, nbT, bnc, (float*)d_out, N, N_pad);
}

// Round 12
// 132.685 us; speedup vs baseline: 1.2941x; 1.2941x over previous
//
#include <hip/hip_runtime.h>

// Sparse residual block via bf16 MFMA, output-centric.
// Round 12: ALL k-loop traffic via global_load_lds (no VGPR-dest loads except
// tiny j-index loads). A-rows GATHERED into LDS (per-lane global src), 256B/128B
// row stride with chunk-XOR swizzle carried in the source address (linear dest,
// swizzled read). B double-buffered, A single-buffered, 2 barriers/step.
// Zero inline asm — every primitive proven correct in R5.

typedef __attribute__((ext_vector_type(8))) short bf16x8;
typedef __attribute__((ext_vector_type(4))) float f32x4;
typedef unsigned short u16;

constexpr int K27  = 27;
constexpr int KPAD = 32;     // nbT k-slots (27..31 always invalid = -1)
constexpr int CIN  = 64;
constexpr int COUT = 96;
constexpr int W1SZ = 6144;   // u16 per k-tile: 12 frags * 512
constexpr int W2SZ = 9216;   // u16 per k-tile: 18 frags * 512

#define MFMA __builtin_amdgcn_mfma_f32_16x16x32_bf16

__device__ __forceinline__ u16 f2bf(float f) {
  unsigned u = __float_as_uint(f);
  return (u16)((u + 0x7FFFu + ((u >> 16) & 1u)) >> 16);
}

__device__ __forceinline__ int posf(int c) {  // c in 0..31, k_local-ordered perm
  return ((c >> 2) & 3) * 8 + (c & 3) + ((c >> 4) & 1) * 4;
}

__device__ __forceinline__ bf16x8 ld16(const u16* p) {
  union { bf16x8 f; uint4 u; } r;
  r.u = *reinterpret_cast<const uint4*>(p);
  return r.f;
}

__device__ __forceinline__ void gll(const u16* g, u16* l) {
  __builtin_amdgcn_global_load_lds(
      (const __attribute__((address_space(1))) unsigned int*)g,
      (__attribute__((address_space(3))) unsigned int*)l, 16, 0, 0);
}

// bijective XCD-aware swizzle (m204 form)
__device__ __forceinline__ int xcd_swz(int bid, int nblk) {
  int q = nblk >> 3, r = nblk & 7;
  int x = bid & 7, i = bid >> 3;
  return (x < r ? x * (q + 1) : r * (q + 1) + (x - r) * q) + i;
}

// ---------------- prep ----------------
__global__ void build_nbT(const int* __restrict__ in_idx, const int* __restrict__ out_idx,
                          int* __restrict__ nbT, int N, int N_pad) {
  int t = blockIdx.x * blockDim.x + threadIdx.x;
  if (t >= K27 * N) return;
  int k = t / N;
  int o = out_idx[t];
  if (o < N) nbT[(size_t)k * N_pad + o] = in_idx[t];
}

__global__ void prep_all(
    const float* __restrict__ x, const float* __restrict__ W1,
    const float* __restrict__ W2, const float* __restrict__ Wd,
    const float* g1, const float* b1, const float* m1, const float* v1,
    const float* g2, const float* b2, const float* m2, const float* v2,
    const float* gd, const float* bd, const float* md, const float* vd,
    u16* __restrict__ xbf, u16* __restrict__ W1t, u16* __restrict__ W2t,
    u16* __restrict__ Wdt, float* __restrict__ bnc, u16* __restrict__ hbf, int N) {
  long i = (long)blockIdx.x * blockDim.x + threadIdx.x;
  const long R0 = (long)(N + 1) * CIN;
  const long R1 = (long)K27 * W1SZ;
  const long R2 = (long)K27 * W2SZ;
  const long R3 = (long)CIN * COUT;
  if (i < R0) {  // x -> bf16, permuted channels; row N zeroed
    int c = (int)(i & 63);
    float v = (i < (long)N * CIN) ? x[i] : 0.f;
    xbf[(i & ~63L) + (c & 32) + posf(c & 31)] = f2bf(v);
    return;
  }
  i -= R0;
  if (i < R1) {  // W1 -> read-order frags: [k][f=c*6+n][lane][j]
    int k = (int)(i / W1SZ), r = (int)(i % W1SZ);
    int f = r >> 9, lane = (r >> 3) & 63, j = r & 7;
    int c = f / 6, n = f % 6, m = lane & 15, g = lane >> 4;
    int co = n * 16 + m;
    int ci = c * 32 + 4 * g + (j & 3) + 16 * (j >> 2);
    W1t[i] = f2bf(W1[((size_t)k * CIN + ci) * COUT + co]);
    return;
  }
  i -= R1;
  if (i < R2) {  // W2 -> read-order frags
    int k = (int)(i / W2SZ), r = (int)(i % W2SZ);
    int f = r >> 9, lane = (r >> 3) & 63, j = r & 7;
    int c = f / 6, n = f % 6, m = lane & 15, g = lane >> 4;
    int co = n * 16 + m;
    int ci = c * 32 + 4 * g + (j & 3) + 16 * (j >> 2);
    W2t[i] = f2bf(W2[((size_t)k * COUT + ci) * COUT + co]);
    return;
  }
  i -= R2;
  if (i < R3) {  // Wd[ci][co] -> Wdt[co][perm(ci)] (register path)
    int ci = (int)(i / COUT), co = (int)(i % COUT);
    Wdt[co * CIN + (ci & 32) + posf(ci & 31)] = f2bf(Wd[i]);
    return;
  }
  i -= R3;
  if (i < 128) {  // zero row N of hbf, 256B wide (covers chunks 0..15)
    hbf[(size_t)N * COUT + i] = 0;
    if (i < COUT) {
      int c = (int)i;
      float A1 = g1[c] * rsqrtf(v1[c] + 1e-5f);
      float A2 = g2[c] * rsqrtf(v2[c] + 1e-5f);
      float Ad = gd[c] * rsqrtf(vd[c] + 1e-5f);
      bnc[c]       = A1;
      bnc[96 + c]  = b1[c] - m1[c] * A1;
      bnc[192 + c] = A2;
      bnc[288 + c] = b2[c] - m2[c] * A2 + bd[c] - md[c] * Ad;
      bnc[384 + c] = Ad / A2;
    }
  }
}

// ---------------- conv1: x(64) -> h(96) bf16, BN+ReLU, permuted store --------
__global__ __launch_bounds__(256, 2) void conv1_mfma(
    const u16* __restrict__ xbf, const u16* __restrict__ W1t,
    const int* __restrict__ nbT, const float* __restrict__ bnc,
    u16* __restrict__ hbf, int N, int N_pad) {
  __shared__ u16 Ab[4096];      // 64 rows x 64 u16 (128B), chunk-swizzled
  __shared__ u16 Bb[2][W1SZ];
  const int t    = threadIdx.x;
  const int lane = t & 63;
  const int m    = lane & 15;
  const int slot = lane >> 4;
  const int w    = t >> 6;
  const int wr   = w >> 1;
  const int wc   = w & 1;
  const int row0 = xcd_swz(blockIdx.x, gridDim.x) * 64;
  const int roww = row0 + wr * 32;

  f32x4 acc[2][3];
#pragma unroll
  for (int s = 0; s < 2; ++s)
#pragma unroll
    for (int n = 0; n < 3; ++n) acc[s][n] = (f32x4){0.f, 0.f, 0.f, 0.f};

  // staging constants: 2 issues/thread, chunk c = (w*2+i)*64+lane, 8 chunks/row
  int rA[2], qsw[2];
#pragma unroll
  for (int i = 0; i < 2; ++i) {
    int c = (w * 2 + i) * 64 + lane;
    int r = c >> 3;
    rA[i]  = r;
    qsw[i] = ((c & 7) ^ (r & 7)) * 8;   // u16 offset of source chunk
  }

  auto loadJ = [&](int kt, int (&jd)[2]) {
#pragma unroll
    for (int i = 0; i < 2; ++i) jd[i] = nbT[(size_t)kt * N_pad + row0 + rA[i]];
  };
  auto stageA = [&](int (&jc)[2]) {
#pragma unroll
    for (int i = 0; i < 2; ++i) {
      int j = jc[i];
      const u16* src = xbf + (size_t)(j < 0 ? N : j) * CIN + qsw[i];
      gll(src, (u16*)Ab + (w * 2 + i) * 512);
    }
  };
  auto stageB = [&](int kt) {
#pragma unroll
    for (int s = 0; s < 3; ++s)
      gll(W1t + (size_t)kt * W1SZ + s * 2048 + t * 8, &Bb[kt & 1][s * 2048 + t * 8]);
  };
  auto compute = [&](int k) {
    const u16* Bc = Bb[k & 1] + wc * 1536 + lane * 8;
    bf16x8 av[2][2];
#pragma unroll
    for (int s = 0; s < 2; ++s) {
      const int row = wr * 32 + s * 16 + m;
      const u16* ar = (const u16*)Ab + row * 64;
      const int rx = row & 7;
#pragma unroll
      for (int c = 0; c < 2; ++c) av[s][c] = ld16(ar + ((slot + c * 4) ^ rx) * 8);
    }
    __builtin_amdgcn_s_setprio(1);
#pragma unroll
    for (int c = 0; c < 2; ++c)
#pragma unroll
      for (int nn = 0; nn < 3; ++nn) {
        bf16x8 B = ld16(Bc + (c * 6 + nn) * 512);
        acc[0][nn] = MFMA(av[0][c], B, acc[0][nn], 0, 0, 0);
        acc[1][nn] = MFMA(av[1][c], B, acc[1][nn], 0, 0, 0);
      }
    __builtin_amdgcn_s_setprio(0);
  };

  int jA[2], jB[2];
  loadJ(0, jA);
  stageB(0);
  stageA(jA);        // A(0)
  loadJ(1, jA);      // j(1) for step 0's stageA
  __syncthreads();   // A(0), B(0) landed

  auto step = [&](int k, int (&jc)[2], int (&jn)[2]) {
    if (k + 1 < K27) stageB(k + 1);
    loadJ(k + 2, jn);
    compute(k);
    __syncthreads();                 // all reads of A(k)/B(k) done; B(k+1) landed
    if (k + 1 < K27) stageA(jc);     // A(k+1) into the (now free) single buffer
    __syncthreads();                 // A(k+1) landed
  };

  for (int kk = 0; kk < K27 - 1; kk += 2) {
    step(kk,     jA, jB);
    step(kk + 1, jB, jA);
  }
  step(K27 - 1, jA, jB);

  const int pbase = ((m >> 2) << 3) + (m & 3);
#pragma unroll
  for (int nn = 0; nn < 3; ++nn) {
    const int n   = wc * 3 + nn;
    const int col = n * 16 + m;
    const int dcol = (n >> 1) * 32 + pbase + ((n & 1) << 2);  // perm pos for conv2 A
    const float sc = bnc[col], bi = bnc[COUT + col];
#pragma unroll
    for (int s = 0; s < 2; ++s)
#pragma unroll
      for (int r = 0; r < 4; ++r) {
        const int row = roww + s * 16 + slot * 4 + r;
        if (row < N)
          hbf[(size_t)row * COUT + dcol] = f2bf(fmaxf(fmaf(acc[s][nn][r], sc, bi), 0.f));
      }
  }
}

// ------- conv2: h(96) -> out(96) f32, + folded skip BN(x@Wd), BN+ReLU --------
__global__ __launch_bounds__(256, 2) void conv2_mfma(
    const u16* __restrict__ hbf, const u16* __restrict__ W2t,
    const u16* __restrict__ xbf, const u16* __restrict__ Wdt,
    const int* __restrict__ nbT, const float* __restrict__ bnc,
    float* __restrict__ out, int N, int N_pad) {
  __shared__ u16 Ab[8192];      // 64 rows x 128 u16 (256B), chunk-swizzled
  __shared__ u16 Bb[2][W2SZ];
  const int t    = threadIdx.x;
  const int lane = t & 63;
  const int m    = lane & 15;
  const int slot = lane >> 4;
  const int w    = t >> 6;
  const int wr   = w >> 1;
  const int wc   = w & 1;
  const int row0 = xcd_swz(blockIdx.x, gridDim.x) * 64;
  const int roww = row0 + wr * 32;

  f32x4 acc[2][3];
#pragma unroll
  for (int s = 0; s < 2; ++s)
#pragma unroll
    for (int n = 0; n < 3; ++n) acc[s][n] = (f32x4){0.f, 0.f, 0.f, 0.f};

  // staging constants: 4 issues/thread, chunk c = (w*4+i)*64+lane, 16 chunks/row
  int rA[4], qsw[4], inv[4];
#pragma unroll
  for (int i = 0; i < 4; ++i) {
    int c = (w * 4 + i) * 64 + lane;
    int r = c >> 4;
    int q = (c & 15) ^ (r & 7);
    rA[i]  = r;
    qsw[i] = q * 8;
    inv[i] = (q >= 12);        // pad chunk -> source = zero row
  }

  auto loadJ = [&](int kt, int (&jd)[4]) {
#pragma unroll
    for (int i = 0; i < 4; ++i) jd[i] = nbT[(size_t)kt * N_pad + row0 + rA[i]];
  };
  auto stageA = [&](int (&jc)[4]) {
#pragma unroll
    for (int i = 0; i < 4; ++i) {
      int j = jc[i];
      int sel = (j < 0 || inv[i]) ? N : j;
      const u16* src = hbf + (size_t)sel * COUT + qsw[i];
      gll(src, (u16*)Ab + (w * 4 + i) * 512);
    }
  };
  auto stageB = [&](int kt) {
    const u16* src = W2t + (size_t)kt * W2SZ;
    u16* dst = Bb[kt & 1];
#pragma unroll
    for (int s = 0; s < 4; ++s) gll(src + s * 2048 + t * 8, dst + s * 2048 + t * 8);
    if (t < 128) gll(src + 8192 + t * 8, dst + 8192 + t * 8);
  };
  auto compute = [&](int k) {
    const u16* Bc = Bb[k & 1] + wc * 1536 + lane * 8;
    bf16x8 av[2][3];
#pragma unroll
    for (int s = 0; s < 2; ++s) {
      const int row = wr * 32 + s * 16 + m;
      const u16* ar = (const u16*)Ab + row * 128;
      const int rx = row & 7;
#pragma unroll
      for (int c = 0; c < 3; ++c) av[s][c] = ld16(ar + ((slot + c * 4) ^ rx) * 8);
    }
    __builtin_amdgcn_s_setprio(1);
#pragma unroll
    for (int c = 0; c < 3; ++c)
#pragma unroll
      for (int nn = 0; nn < 3; ++nn) {
        bf16x8 B = ld16(Bc + (c * 6 + nn) * 512);
        acc[0][nn] = MFMA(av[0][c], B, acc[0][nn], 0, 0, 0);
        acc[1][nn] = MFMA(av[1][c], B, acc[1][nn], 0, 0, 0);
      }
    __builtin_amdgcn_s_setprio(0);
  };

  int jA[4], jB[4];
  loadJ(0, jA);
  stageB(0);
  stageA(jA);        // A(0)
  loadJ(1, jA);      // j(1)

  // skip path: x @ Wd on own rows, pre-scaled by Ad/A2 (overlaps staging)
  {
    int r0 = roww + m, r1 = roww + 16 + m;
    const u16* pa = xbf + (size_t)(r0 < N ? r0 : N) * CIN + slot * 8;
    const u16* pb = xbf + (size_t)(r1 < N ? r1 : N) * CIN + slot * 8;
    bf16x8 S0a = ld16(pa), S1a = ld16(pa + 32);
    bf16x8 S0b = ld16(pb), S1b = ld16(pb + 32);
#pragma unroll
    for (int nn = 0; nn < 3; ++nn) {
      const int col = (wc * 3 + nn) * 16 + m;
      const u16* wd = Wdt + col * CIN + slot * 8;
      bf16x8 B0 = ld16(wd), B1 = ld16(wd + 32);
      acc[0][nn] = MFMA(S0a, B0, acc[0][nn], 0, 0, 0);
      acc[0][nn] = MFMA(S1a, B1, acc[0][nn], 0, 0, 0);
      acc[1][nn] = MFMA(S0b, B0, acc[1][nn], 0, 0, 0);
      acc[1][nn] = MFMA(S1b, B1, acc[1][nn], 0, 0, 0);
    }
#pragma unroll
    for (int nn = 0; nn < 3; ++nn) {
      float rr = bnc[384 + (wc * 3 + nn) * 16 + m];
      acc[0][nn] *= rr;
      acc[1][nn] *= rr;
    }
  }
  __syncthreads();   // A(0), B(0) landed

  auto step = [&](int k, int (&jc)[4], int (&jn)[4]) {
    if (k + 1 < K27) stageB(k + 1);
    loadJ(k + 2, jn);
    compute(k);
    __syncthreads();
    if (k + 1 < K27) stageA(jc);
    __syncthreads();
  };

  for (int kk = 0; kk < K27 - 1; kk += 2) {
    step(kk,     jA, jB);
    step(kk + 1, jB, jA);
  }
  step(K27 - 1, jA, jB);

#pragma unroll
  for (int nn = 0; nn < 3; ++nn) {
    const int col = (wc * 3 + nn) * 16 + m;
    const float sc = bnc[192 + col], bi = bnc[288 + col];
#pragma unroll
    for (int s = 0; s < 2; ++s)
#pragma unroll
      for (int r = 0; r < 4; ++r) {
        const int row = roww + s * 16 + slot * 4 + r;
        if (row < N)
          out[(size_t)row * COUT + col] = fmaxf(fmaf(acc[s][nn][r], sc, bi), 0.f);
      }
  }
}

// ---------------- launch ----------------
extern "C" void kernel_launch(void* const* d_in, const int* in_sizes, int n_in,
                              void* d_out, int out_size, void* d_ws, size_t ws_size,
                              hipStream_t stream) {
  const float* x  = (const float*)d_in[0];
  const float* W1 = (const float*)d_in[1];
  const float* g1 = (const float*)d_in[2];
  const float* b1 = (const float*)d_in[3];
  const float* m1 = (const float*)d_in[4];
  const float* v1 = (const float*)d_in[5];
  const float* W2 = (const float*)d_in[6];
  const float* g2 = (const float*)d_in[7];
  const float* b2 = (const float*)d_in[8];
  const float* m2 = (const float*)d_in[9];
  const float* v2 = (const float*)d_in[10];
  const float* Wd = (const float*)d_in[11];
  const float* gd = (const float*)d_in[12];
  const float* bd = (const float*)d_in[13];
  const float* md = (const float*)d_in[14];
  const float* vd = (const float*)d_in[15];
  const int* in_idx  = (const int*)d_in[16];
  const int* out_idx = (const int*)d_in[17];

  const int N  = in_sizes[0] / CIN;
  const int GB = (N + 63) / 64;
  const int N_pad = GB * 64;

  char* ws = (char*)d_ws;
  size_t off = 0;
  auto alloc = [&](size_t bytes) { size_t o = off; off = (off + bytes + 255) & ~(size_t)255; return o; };
  int*   nbT = (int*)(ws + alloc((size_t)KPAD * N_pad * sizeof(int)));
  u16*   xbf = (u16*)(ws + alloc((size_t)(N + 1) * CIN * sizeof(u16)));
  u16*   hbf = (u16*)(ws + alloc((size_t)(N + 2) * COUT * sizeof(u16)));
  u16*   W1t = (u16*)(ws + alloc((size_t)K27 * W1SZ * sizeof(u16)));
  u16*   W2t = (u16*)(ws + alloc((size_t)K27 * W2SZ * sizeof(u16)));
  u16*   Wdt = (u16*)(ws + alloc((size_t)COUT * CIN * sizeof(u16)));
  float* bnc = (float*)(ws + alloc(5 * 96 * sizeof(float)));

  hipMemsetAsync(nbT, 0xFF, (size_t)KPAD * N_pad * sizeof(int), stream);
  build_nbT<<<(K27 * N + 255) / 256, 256, 0, stream>>>(in_idx, out_idx, nbT, N, N_pad);

  long ptotal = (long)(N + 1) * CIN + (long)K27 * W1SZ + (long)K27 * W2SZ +
                (long)CIN * COUT + 128;
  prep_all<<<(int)((ptotal + 255) / 256), 256, 0, stream>>>(
      x, W1, W2, Wd, g1, b1, m1, v1, g2, b2, m2, v2, gd, bd, md, vd,
      xbf, W1t, W2t, Wdt, bnc, hbf, N);

  conv1_mfma<<<GB, 256, 0, stream>>>(xbf, W1t, nbT, bnc, hbf, N, N_pad);
  conv2_mfma<<<GB, 256, 0, stream>>>(hbf, W2t, xbf, Wdt, nbT, bnc, (float*)d_out, N, N_pad);
}